// Round 1
// baseline (2777.649 us; speedup 1.0000x reference)
//
#include <hip/hip_runtime.h>
#include <cstddef>

#define HIDDEN 128

__device__ inline float4 shfl_xor4(float4 v, int m) {
    float4 r;
    r.x = __shfl_xor(v.x, m);
    r.y = __shfl_xor(v.y, m);
    r.z = __shfl_xor(v.z, m);
    r.w = __shfl_xor(v.w, m);
    return r;
}

// ---------------------------------------------------------------------------
// Generic row-block GEMM: OUT(nrows x COLS) = IN(nrows x 128) @ W(128 x COLS)
// 64 rows per block, 256 threads. Thread (rg,cg): rows rg*8..+7, cols cg*CPT..
// ---------------------------------------------------------------------------
template <int COLS>
__global__ __launch_bounds__(256, 2) void rowgemm_kernel(
    const float* __restrict__ in, const float* __restrict__ W,
    float* __restrict__ out, int nrows)
{
    constexpr int CPT = COLS / 32;  // 4 or 8 cols per thread
    __shared__ float ldsA[64 * HIDDEN];  // 32 KB
    const int row0 = blockIdx.x * 64;
    const int t = threadIdx.x;

    {   // stage 64x128 row tile (zero-pad past nrows); fully coalesced
        const float4* in4 = (const float4*)in;
        float4* lds4 = (float4*)ldsA;
#pragma unroll
        for (int s = 0; s < 8; ++s) {
            int idx = t + s * 256;          // float4 index within tile
            int r = idx >> 5;               // 32 float4 per row
            int grow = row0 + r;
            float4 v = make_float4(0.f, 0.f, 0.f, 0.f);
            if (grow < nrows) v = in4[(size_t)grow * 32 + (idx & 31)];
            lds4[idx] = v;
        }
    }
    __syncthreads();

    const int cg = t & 31, rg = t >> 5;
    float4 acc0[8], acc1[8];
#pragma unroll
    for (int i = 0; i < 8; ++i) {
        acc0[i] = make_float4(0.f, 0.f, 0.f, 0.f);
        if constexpr (CPT == 8) acc1[i] = make_float4(0.f, 0.f, 0.f, 0.f);
    }
    const float4* lds4 = (const float4*)ldsA;
    const float4* W4 = (const float4*)W;

    for (int k4 = 0; k4 < 32; ++k4) {
        float4 a[8];
#pragma unroll
        for (int i = 0; i < 8; ++i) a[i] = lds4[(rg * 8 + i) * 32 + k4];
#pragma unroll
        for (int kk = 0; kk < 4; ++kk) {
            const int k = k4 * 4 + kk;
            float4 b0 = W4[(k * COLS + cg * CPT) >> 2];
            float4 b1;
            if constexpr (CPT == 8) b1 = W4[((k * COLS + cg * CPT) >> 2) + 1];
#pragma unroll
            for (int i = 0; i < 8; ++i) {
                const float av = (kk == 0) ? a[i].x : (kk == 1) ? a[i].y
                               : (kk == 2) ? a[i].z : a[i].w;
                acc0[i].x = fmaf(av, b0.x, acc0[i].x);
                acc0[i].y = fmaf(av, b0.y, acc0[i].y);
                acc0[i].z = fmaf(av, b0.z, acc0[i].z);
                acc0[i].w = fmaf(av, b0.w, acc0[i].w);
                if constexpr (CPT == 8) {
                    acc1[i].x = fmaf(av, b1.x, acc1[i].x);
                    acc1[i].y = fmaf(av, b1.y, acc1[i].y);
                    acc1[i].z = fmaf(av, b1.z, acc1[i].z);
                    acc1[i].w = fmaf(av, b1.w, acc1[i].w);
                }
            }
        }
    }

#pragma unroll
    for (int i = 0; i < 8; ++i) {
        int grow = row0 + rg * 8 + i;
        if (grow < nrows) {
            float4* o4 = (float4*)(out + (size_t)grow * COLS + cg * CPT);
            o4[0] = acc0[i];
            if constexpr (CPT == 8) o4[1] = acc1[i];
        }
    }
}

// ---------------------------------------------------------------------------
// Fused edge kernel: b = IR@Wb (tile in registers), then per-edge logits.
//   logit[m,h] = sum_d qg[c]*(kg[c]*(1+bm[c]) + ba[c]) / norm, c = d*8+h
//   bm[c] = b[m,c] (cols 0..127, held by cg<16), ba[c] = b[m,128+c] (cg>=16).
// Writes pair_logits (output #2) and atomically accumulates segsum = sum exp.
// ---------------------------------------------------------------------------
__global__ __launch_bounds__(256, 2) void edge_logit_kernel(
    const float* __restrict__ ir, const float* __restrict__ Wb,
    const float* __restrict__ qtab, const float* __restrict__ kvtab,
    const int* __restrict__ qidx, const int* __restrict__ kidx,
    const float* __restrict__ normalizer,
    float* __restrict__ pair_logits, float* __restrict__ segsum, int M)
{
    constexpr int COLS = 256;
    __shared__ float ldsA[64 * HIDDEN];
    const int row0 = blockIdx.x * 64;
    const int t = threadIdx.x;

    {   // stage 64x128 IR tile
        const float4* in4 = (const float4*)ir;
        float4* lds4 = (float4*)ldsA;
#pragma unroll
        for (int s = 0; s < 8; ++s) {
            int idx = t + s * 256;
            int r = idx >> 5;
            int grow = row0 + r;
            float4 v = make_float4(0.f, 0.f, 0.f, 0.f);
            if (grow < M) v = in4[(size_t)grow * 32 + (idx & 31)];
            lds4[idx] = v;
        }
    }
    __syncthreads();

    const int cg = t & 31, rg = t >> 5;
    float4 acc0[8], acc1[8];
#pragma unroll
    for (int i = 0; i < 8; ++i) {
        acc0[i] = make_float4(0.f, 0.f, 0.f, 0.f);
        acc1[i] = make_float4(0.f, 0.f, 0.f, 0.f);
    }
    const float4* lds4 = (const float4*)ldsA;
    const float4* W4 = (const float4*)Wb;

    for (int k4 = 0; k4 < 32; ++k4) {
        float4 a[8];
#pragma unroll
        for (int i = 0; i < 8; ++i) a[i] = lds4[(rg * 8 + i) * 32 + k4];
#pragma unroll
        for (int kk = 0; kk < 4; ++kk) {
            const int k = k4 * 4 + kk;
            float4 b0 = W4[(k * COLS + cg * 8) >> 2];
            float4 b1 = W4[((k * COLS + cg * 8) >> 2) + 1];
#pragma unroll
            for (int i = 0; i < 8; ++i) {
                const float av = (kk == 0) ? a[i].x : (kk == 1) ? a[i].y
                               : (kk == 2) ? a[i].z : a[i].w;
                acc0[i].x = fmaf(av, b0.x, acc0[i].x);
                acc0[i].y = fmaf(av, b0.y, acc0[i].y);
                acc0[i].z = fmaf(av, b0.z, acc0[i].z);
                acc0[i].w = fmaf(av, b0.w, acc0[i].w);
                acc1[i].x = fmaf(av, b1.x, acc1[i].x);
                acc1[i].y = fmaf(av, b1.y, acc1[i].y);
                acc1[i].z = fmaf(av, b1.z, acc1[i].z);
                acc1[i].w = fmaf(av, b1.w, acc1[i].w);
            }
        }
    }

    // ---- epilogue: per-edge logits -------------------------------------
    const float nvn = fminf(fmaxf(normalizer[0], 1.0f), 16.0f);
    const float invnorm = 1.0f / nvn;

#pragma unroll
    for (int i = 0; i < 8; ++i) {
        const int m = row0 + rg * 8 + i;
        // bias_add comes from partner lane (cg^16 holds cols c+128)
        float4 ba0 = shfl_xor4(acc0[i], 16);
        float4 ba1 = shfl_xor4(acc1[i], 16);

        float red[8] = {0.f, 0.f, 0.f, 0.f, 0.f, 0.f, 0.f, 0.f};
        if (m < M && cg < 16) {
            const int qi = qidx[m], ki = kidx[m];
            const float4* qp = (const float4*)(qtab + (size_t)qi * 128 + cg * 8);
            const float4 q0 = qp[0], q1 = qp[1];
            const float4* kp = (const float4*)(kvtab + (size_t)ki * 256 + cg * 8);
            const float4 k0 = kp[0], k1 = kp[1];
            red[0] = q0.x * (k0.x * (1.f + acc0[i].x) + ba0.x);
            red[1] = q0.y * (k0.y * (1.f + acc0[i].y) + ba0.y);
            red[2] = q0.z * (k0.z * (1.f + acc0[i].z) + ba0.z);
            red[3] = q0.w * (k0.w * (1.f + acc0[i].w) + ba0.w);
            red[4] = q1.x * (k1.x * (1.f + acc1[i].x) + ba1.x);
            red[5] = q1.y * (k1.y * (1.f + acc1[i].y) + ba1.y);
            red[6] = q1.z * (k1.z * (1.f + acc1[i].z) + ba1.z);
            red[7] = q1.w * (k1.w * (1.f + acc1[i].w) + ba1.w);
        }
        // reduce over the 16 cg lanes (lane bits 0..3); c%8 == j by layout
#pragma unroll
        for (int j = 0; j < 8; ++j) {
            red[j] += __shfl_xor(red[j], 1);
            red[j] += __shfl_xor(red[j], 2);
            red[j] += __shfl_xor(red[j], 4);
            red[j] += __shfl_xor(red[j], 8);
        }
        if (cg == i && m < M) {
            const int qi = qidx[m];
            float l[8];
#pragma unroll
            for (int j = 0; j < 8; ++j) l[j] = red[j] * invnorm;
            float4* po = (float4*)(pair_logits + (size_t)m * 8);
            po[0] = make_float4(l[0], l[1], l[2], l[3]);
            po[1] = make_float4(l[4], l[5], l[6], l[7]);
#pragma unroll
            for (int j = 0; j < 8; ++j)
                atomicAdd(segsum + (size_t)qi * 8 + j, __expf(l[j]));
        }
    }
}

// ---------------------------------------------------------------------------
// Scatter: agg[qi, c] += exp(logit[m, c%8]) / segsum[qi, c%8] * v[ki, c]
// 8 edges per block, each thread one float4 of channels.
// ---------------------------------------------------------------------------
__global__ __launch_bounds__(256) void edge_scatter_kernel(
    const float* __restrict__ pair_logits, const float* __restrict__ segsum,
    const float* __restrict__ kvtab,
    const int* __restrict__ qidx, const int* __restrict__ kidx,
    float* __restrict__ agg, int M)
{
    const int t = threadIdx.x;
    const int m = blockIdx.x * 8 + (t >> 5);
    if (m >= M) return;
    const int c4 = (t & 31) * 4;          // channel base, multiple of 4
    const int qi = qidx[m], ki = kidx[m];
    const float4 l4  = *(const float4*)(pair_logits + (size_t)m * 8 + (c4 & 4));
    const float4 ss4 = *(const float4*)(segsum + (size_t)qi * 8 + (c4 & 4));
    const float4 v4  = *(const float4*)(kvtab + (size_t)ki * 256 + 128 + c4);
    float* ap = agg + (size_t)qi * 128 + c4;
    atomicAdd(ap + 0, __expf(l4.x) / ss4.x * v4.x);
    atomicAdd(ap + 1, __expf(l4.y) / ss4.y * v4.y);
    atomicAdd(ap + 2, __expf(l4.z) / ss4.z * v4.z);
    atomicAdd(ap + 3, __expf(l4.w) / ss4.w * v4.w);
}

// ---------------------------------------------------------------------------
extern "C" void kernel_launch(void* const* d_in, const int* in_sizes, int n_in,
                              void* d_out, int out_size, void* d_ws, size_t ws_size,
                              hipStream_t stream)
{
    const float* query = (const float*)d_in[0];
    const float* key   = (const float*)d_in[1];
    const float* ir    = (const float*)d_in[2];
    const int*   qidx  = (const int*)d_in[3];
    const int*   kidx  = (const int*)d_in[4];
    const float* Wq    = (const float*)d_in[5];
    const float* Wkv   = (const float*)d_in[6];
    const float* Wb    = (const float*)d_in[7];
    const float* Wo    = (const float*)d_in[8];
    const float* normalizer = (const float*)d_in[9];

    const int N = in_sizes[0] / HIDDEN;   // 50000
    const int M = in_sizes[3];            // 800000

    float* out_result  = (float*)d_out;                        // N*128
    float* pair_logits = (float*)d_out + (size_t)N * HIDDEN;   // M*8

    // workspace layout (floats): agg | segsum | qtab | kvtab  (~104 MB)
    float* agg    = (float*)d_ws;                  // N*128
    float* segsum = agg + (size_t)N * 128;         // N*8
    float* qtab   = segsum + (size_t)N * 8;        // N*128
    float* kvtab  = qtab + (size_t)N * 128;        // N*256

    // zero accumulators (agg and segsum are adjacent)
    hipMemsetAsync(agg, 0, (size_t)(N * 128 + N * 8) * sizeof(float), stream);

    const int rgrid = (N + 63) / 64;
    rowgemm_kernel<128><<<rgrid, 256, 0, stream>>>(query, Wq, qtab, N);
    rowgemm_kernel<256><<<rgrid, 256, 0, stream>>>(key, Wkv, kvtab, N);

    edge_logit_kernel<<<(M + 63) / 64, 256, 0, stream>>>(
        ir, Wb, qtab, kvtab, qidx, kidx, normalizer, pair_logits, segsum, M);

    edge_scatter_kernel<<<(M + 7) / 8, 256, 0, stream>>>(
        pair_logits, segsum, kvtab, qidx, kidx, agg, M);

    rowgemm_kernel<128><<<rgrid, 256, 0, stream>>>(agg, Wo, out_result, N);
}

// Round 2
// 1707.105 us; speedup vs baseline: 1.6271x; 1.6271x over previous
//
#include <hip/hip_runtime.h>
#include <cstddef>

#define HIDDEN 128

__device__ inline float4 shfl_xor4(float4 v, int m) {
    float4 r;
    r.x = __shfl_xor(v.x, m);
    r.y = __shfl_xor(v.y, m);
    r.z = __shfl_xor(v.z, m);
    r.w = __shfl_xor(v.w, m);
    return r;
}

// ---------------------------------------------------------------------------
// Generic row-block GEMM: OUT(nrows x COLS) = IN(nrows x 128) @ W(128 x COLS)
// 64 rows per block, 256 threads. Thread (rg,cg): rows rg*8..+7, cols cg*CPT..
// ---------------------------------------------------------------------------
template <int COLS>
__global__ __launch_bounds__(256, 2) void rowgemm_kernel(
    const float* __restrict__ in, const float* __restrict__ W,
    float* __restrict__ out, int nrows)
{
    constexpr int CPT = COLS / 32;  // 4 or 8 cols per thread
    __shared__ float ldsA[64 * HIDDEN];  // 32 KB
    const int row0 = blockIdx.x * 64;
    const int t = threadIdx.x;

    {   // stage 64x128 row tile (zero-pad past nrows); fully coalesced
        const float4* in4 = (const float4*)in;
        float4* lds4 = (float4*)ldsA;
#pragma unroll
        for (int s = 0; s < 8; ++s) {
            int idx = t + s * 256;          // float4 index within tile
            int r = idx >> 5;               // 32 float4 per row
            int grow = row0 + r;
            float4 v = make_float4(0.f, 0.f, 0.f, 0.f);
            if (grow < nrows) v = in4[(size_t)grow * 32 + (idx & 31)];
            lds4[idx] = v;
        }
    }
    __syncthreads();

    const int cg = t & 31, rg = t >> 5;
    float4 acc0[8], acc1[8];
#pragma unroll
    for (int i = 0; i < 8; ++i) {
        acc0[i] = make_float4(0.f, 0.f, 0.f, 0.f);
        if constexpr (CPT == 8) acc1[i] = make_float4(0.f, 0.f, 0.f, 0.f);
    }
    const float4* lds4 = (const float4*)ldsA;
    const float4* W4 = (const float4*)W;

    for (int k4 = 0; k4 < 32; ++k4) {
        float4 a[8];
#pragma unroll
        for (int i = 0; i < 8; ++i) a[i] = lds4[(rg * 8 + i) * 32 + k4];
#pragma unroll
        for (int kk = 0; kk < 4; ++kk) {
            const int k = k4 * 4 + kk;
            float4 b0 = W4[(k * COLS + cg * CPT) >> 2];
            float4 b1;
            if constexpr (CPT == 8) b1 = W4[((k * COLS + cg * CPT) >> 2) + 1];
#pragma unroll
            for (int i = 0; i < 8; ++i) {
                const float av = (kk == 0) ? a[i].x : (kk == 1) ? a[i].y
                               : (kk == 2) ? a[i].z : a[i].w;
                acc0[i].x = fmaf(av, b0.x, acc0[i].x);
                acc0[i].y = fmaf(av, b0.y, acc0[i].y);
                acc0[i].z = fmaf(av, b0.z, acc0[i].z);
                acc0[i].w = fmaf(av, b0.w, acc0[i].w);
                if constexpr (CPT == 8) {
                    acc1[i].x = fmaf(av, b1.x, acc1[i].x);
                    acc1[i].y = fmaf(av, b1.y, acc1[i].y);
                    acc1[i].z = fmaf(av, b1.z, acc1[i].z);
                    acc1[i].w = fmaf(av, b1.w, acc1[i].w);
                }
            }
        }
    }

#pragma unroll
    for (int i = 0; i < 8; ++i) {
        int grow = row0 + rg * 8 + i;
        if (grow < nrows) {
            float4* o4 = (float4*)(out + (size_t)grow * COLS + cg * CPT);
            o4[0] = acc0[i];
            if constexpr (CPT == 8) o4[1] = acc1[i];
        }
    }
}

// ---------------------------------------------------------------------------
// Fused edge kernel: b = IR@Wb (tile in registers), then per-edge logits.
//   logit[m,h] = sum_d qg[c]*(kg[c]*(1+bm[c]) + ba[c]) / norm, c = d*8+h
// Writes pair_logits only (softmax handled downstream by node_agg).
// ---------------------------------------------------------------------------
__global__ __launch_bounds__(256, 2) void edge_logit_kernel(
    const float* __restrict__ ir, const float* __restrict__ Wb,
    const float* __restrict__ qtab, const float* __restrict__ kvtab,
    const int* __restrict__ qidx, const int* __restrict__ kidx,
    const float* __restrict__ normalizer,
    float* __restrict__ pair_logits, int M)
{
    constexpr int COLS = 256;
    __shared__ float ldsA[64 * HIDDEN];
    const int row0 = blockIdx.x * 64;
    const int t = threadIdx.x;

    {   // stage 64x128 IR tile
        const float4* in4 = (const float4*)ir;
        float4* lds4 = (float4*)ldsA;
#pragma unroll
        for (int s = 0; s < 8; ++s) {
            int idx = t + s * 256;
            int r = idx >> 5;
            int grow = row0 + r;
            float4 v = make_float4(0.f, 0.f, 0.f, 0.f);
            if (grow < M) v = in4[(size_t)grow * 32 + (idx & 31)];
            lds4[idx] = v;
        }
    }
    __syncthreads();

    const int cg = t & 31, rg = t >> 5;
    float4 acc0[8], acc1[8];
#pragma unroll
    for (int i = 0; i < 8; ++i) {
        acc0[i] = make_float4(0.f, 0.f, 0.f, 0.f);
        acc1[i] = make_float4(0.f, 0.f, 0.f, 0.f);
    }
    const float4* lds4 = (const float4*)ldsA;
    const float4* W4 = (const float4*)Wb;

    for (int k4 = 0; k4 < 32; ++k4) {
        float4 a[8];
#pragma unroll
        for (int i = 0; i < 8; ++i) a[i] = lds4[(rg * 8 + i) * 32 + k4];
#pragma unroll
        for (int kk = 0; kk < 4; ++kk) {
            const int k = k4 * 4 + kk;
            float4 b0 = W4[(k * COLS + cg * 8) >> 2];
            float4 b1 = W4[((k * COLS + cg * 8) >> 2) + 1];
#pragma unroll
            for (int i = 0; i < 8; ++i) {
                const float av = (kk == 0) ? a[i].x : (kk == 1) ? a[i].y
                               : (kk == 2) ? a[i].z : a[i].w;
                acc0[i].x = fmaf(av, b0.x, acc0[i].x);
                acc0[i].y = fmaf(av, b0.y, acc0[i].y);
                acc0[i].z = fmaf(av, b0.z, acc0[i].z);
                acc0[i].w = fmaf(av, b0.w, acc0[i].w);
                acc1[i].x = fmaf(av, b1.x, acc1[i].x);
                acc1[i].y = fmaf(av, b1.y, acc1[i].y);
                acc1[i].z = fmaf(av, b1.z, acc1[i].z);
                acc1[i].w = fmaf(av, b1.w, acc1[i].w);
            }
        }
    }

    // ---- epilogue: per-edge logits -------------------------------------
    const float nvn = fminf(fmaxf(normalizer[0], 1.0f), 16.0f);
    const float invnorm = 1.0f / nvn;

#pragma unroll
    for (int i = 0; i < 8; ++i) {
        const int m = row0 + rg * 8 + i;
        // bias_add comes from partner lane (cg^16 holds cols c+128)
        float4 ba0 = shfl_xor4(acc0[i], 16);
        float4 ba1 = shfl_xor4(acc1[i], 16);

        float red[8] = {0.f, 0.f, 0.f, 0.f, 0.f, 0.f, 0.f, 0.f};
        if (m < M && cg < 16) {
            const int qi = qidx[m], ki = kidx[m];
            const float4* qp = (const float4*)(qtab + (size_t)qi * 128 + cg * 8);
            const float4 q0 = qp[0], q1 = qp[1];
            const float4* kp = (const float4*)(kvtab + (size_t)ki * 256 + cg * 8);
            const float4 k0 = kp[0], k1 = kp[1];
            red[0] = q0.x * (k0.x * (1.f + acc0[i].x) + ba0.x);
            red[1] = q0.y * (k0.y * (1.f + acc0[i].y) + ba0.y);
            red[2] = q0.z * (k0.z * (1.f + acc0[i].z) + ba0.z);
            red[3] = q0.w * (k0.w * (1.f + acc0[i].w) + ba0.w);
            red[4] = q1.x * (k1.x * (1.f + acc1[i].x) + ba1.x);
            red[5] = q1.y * (k1.y * (1.f + acc1[i].y) + ba1.y);
            red[6] = q1.z * (k1.z * (1.f + acc1[i].z) + ba1.z);
            red[7] = q1.w * (k1.w * (1.f + acc1[i].w) + ba1.w);
        }
        // reduce over the 16 cg lanes (lane bits 0..3); c%8 == j by layout
#pragma unroll
        for (int j = 0; j < 8; ++j) {
            red[j] += __shfl_xor(red[j], 1);
            red[j] += __shfl_xor(red[j], 2);
            red[j] += __shfl_xor(red[j], 4);
            red[j] += __shfl_xor(red[j], 8);
        }
        if (cg == i && m < M) {
            float4* po = (float4*)(pair_logits + (size_t)m * 8);
            po[0] = make_float4(red[0] * invnorm, red[1] * invnorm,
                                red[2] * invnorm, red[3] * invnorm);
            po[1] = make_float4(red[4] * invnorm, red[5] * invnorm,
                                red[6] * invnorm, red[7] * invnorm);
        }
    }
}

// ---------------------------------------------------------------------------
// CSR build: histogram -> block scan -> placement
// ---------------------------------------------------------------------------
__global__ __launch_bounds__(256) void hist_kernel(
    const int* __restrict__ qidx, int* __restrict__ cnt, int M)
{
    int m = blockIdx.x * 256 + threadIdx.x;
    if (m < M) atomicAdd(&cnt[qidx[m]], 1);
}

__global__ __launch_bounds__(256) void scan_kernel(
    const int* __restrict__ cnt, int* __restrict__ rowptr,
    int* __restrict__ wptr, int N)
{
    __shared__ int sums[256];
    const int t = threadIdx.x;
    const int chunk = (N + 255) / 256;
    const int b = t * chunk;
    const int e = min(b + chunk, N);
    int s = 0;
    for (int i = b; i < e; ++i) s += cnt[i];
    sums[t] = s;
    __syncthreads();
    // inclusive log-step scan over 256 partials
    for (int off = 1; off < 256; off <<= 1) {
        int v = (t >= off) ? sums[t - off] : 0;
        __syncthreads();
        sums[t] += v;
        __syncthreads();
    }
    int run = (t == 0) ? 0 : sums[t - 1];
    for (int i = b; i < e; ++i) {
        rowptr[i] = run;
        wptr[i] = run;
        run += cnt[i];
    }
    if (t == 255) rowptr[N] = sums[255];
}

__global__ __launch_bounds__(256) void place_kernel(
    const int* __restrict__ qidx, int* __restrict__ wptr,
    int* __restrict__ csr, int M)
{
    int m = blockIdx.x * 256 + threadIdx.x;
    if (m < M) {
        int p = atomicAdd(&wptr[qidx[m]], 1);
        csr[p] = m;
    }
}

// ---------------------------------------------------------------------------
// Per-node softmax + weighted V aggregation. One wave per node, no atomics.
// lane owns channels (lane) and (lane+64); h = lane & 7 matches c % 8.
// ---------------------------------------------------------------------------
__global__ __launch_bounds__(256) void node_agg_kernel(
    const float* __restrict__ pl, const float* __restrict__ kvtab,
    const int* __restrict__ kidx, const int* __restrict__ rowptr,
    const int* __restrict__ csr, float* __restrict__ agg, int N)
{
    const int node = blockIdx.x * 4 + (threadIdx.x >> 6);
    if (node >= N) return;
    const int lane = threadIdx.x & 63;
    const int h = lane & 7;
    const int beg = rowptr[node], end = rowptr[node + 1];

    float s = 0.f;
    for (int e = beg; e < end; ++e) {
        int m = csr[e];
        s += __expf(pl[(size_t)m * 8 + h]);
    }
    const float inv = 1.0f / s;

    float acc0 = 0.f, acc1 = 0.f;
    for (int e = beg; e < end; ++e) {
        int m = csr[e];
        float w = __expf(pl[(size_t)m * 8 + h]) * inv;
        const float* vp = kvtab + (size_t)kidx[m] * 256 + 128;
        acc0 = fmaf(w, vp[lane], acc0);
        acc1 = fmaf(w, vp[lane + 64], acc1);
    }
    agg[(size_t)node * 128 + lane] = acc0;
    agg[(size_t)node * 128 + 64 + lane] = acc1;
}

// ---------------------------------------------------------------------------
extern "C" void kernel_launch(void* const* d_in, const int* in_sizes, int n_in,
                              void* d_out, int out_size, void* d_ws, size_t ws_size,
                              hipStream_t stream)
{
    const float* query = (const float*)d_in[0];
    const float* key   = (const float*)d_in[1];
    const float* ir    = (const float*)d_in[2];
    const int*   qidx  = (const int*)d_in[3];
    const int*   kidx  = (const int*)d_in[4];
    const float* Wq    = (const float*)d_in[5];
    const float* Wkv   = (const float*)d_in[6];
    const float* Wb    = (const float*)d_in[7];
    const float* Wo    = (const float*)d_in[8];
    const float* normalizer = (const float*)d_in[9];

    const int N = in_sizes[0] / HIDDEN;   // 50000
    const int M = in_sizes[3];            // 800000

    float* out_result  = (float*)d_out;                        // N*128
    float* pair_logits = (float*)d_out + (size_t)N * HIDDEN;   // M*8

    // qtab borrows the out_result region (dead until the final GEMM).
    float* qtab = out_result;

    // workspace layout: agg(N*128 f, cnt aliases its head) | kvtab(N*256 f)
    //                   | rowptr(N+1 i) | wptr(N i) | csr(M i)   ~= 80 MB
    float* agg    = (float*)d_ws;
    int*   cnt    = (int*)d_ws;                          // dead before agg lives
    float* kvtab  = agg + (size_t)N * 128;
    int*   rowptr = (int*)(kvtab + (size_t)N * 256);
    int*   wptr   = rowptr + (N + 1);
    int*   csr    = wptr + N;

    const int rgrid = (N + 63) / 64;
    const int mgrid = (M + 255) / 256;

    // CSR build
    hipMemsetAsync(cnt, 0, (size_t)N * sizeof(int), stream);
    hist_kernel<<<mgrid, 256, 0, stream>>>(qidx, cnt, M);
    scan_kernel<<<1, 256, 0, stream>>>(cnt, rowptr, wptr, N);
    place_kernel<<<mgrid, 256, 0, stream>>>(qidx, wptr, csr, M);

    // projections
    rowgemm_kernel<128><<<rgrid, 256, 0, stream>>>(query, Wq, qtab, N);
    rowgemm_kernel<256><<<rgrid, 256, 0, stream>>>(key, Wkv, kvtab, N);

    // fused b-GEMM + per-edge logits
    edge_logit_kernel<<<(M + 63) / 64, 256, 0, stream>>>(
        ir, Wb, qtab, kvtab, qidx, kidx, normalizer, pair_logits, M);

    // per-node softmax + V aggregation (no atomics)
    node_agg_kernel<<<(N + 3) / 4, 256, 0, stream>>>(
        pair_logits, kvtab, kidx, rowptr, csr, agg, N);

    // output projection
    rowgemm_kernel<128><<<rgrid, 256, 0, stream>>>(agg, Wo, out_result, N);
}